// Round 8
// baseline (646.259 us; speedup 1.0000x reference)
//
#include <hip/hip_runtime.h>
#include <math.h>

#define BZ 32
#define SRC_LEN 2048
#define DIM 1024
#define NSPAN 64
#define REP_F 16   // flash reps (surface in rocprof top-5)
#define REP_S 8    // small-kernel reps (solve their compute from total)

typedef float f4 __attribute__((ext_vector_type(4)));

// ---- shared row-matvec core (unchanged math from R4/R5) --------------------
__device__ __forceinline__ void rowmv(const float* __restrict__ Wrow0,
                                      const float* __restrict__ Wrow1,
                                      const float* __restrict__ act,
                                      float (*al)[260],
                                      float* acc0, float* acc1,
                                      int lane, int wave) {
#pragma unroll
    for (int i = 0; i < BZ; ++i) { acc0[i] = 0.f; acc1[i] = 0.f; }
    for (int ks = 0; ks < 4; ++ks) {
        __syncthreads();
#pragma unroll
        for (int j = 0; j < 8; ++j) {
            const int b = wave * 8 + j;
            *(float4*)&al[b][4 * lane] =
                *(const float4*)&act[b * DIM + ks * 256 + 4 * lane];
        }
        __syncthreads();
        const float4 w0 = *(const float4*)&Wrow0[ks * 256 + 4 * lane];
        const float4 w1 = *(const float4*)&Wrow1[ks * 256 + 4 * lane];
#pragma unroll
        for (int b = 0; b < BZ; ++b) {
            const float4 a = *(const float4*)&al[b][4 * lane];
            acc0[b] += w0.x * a.x + w0.y * a.y + w0.z * a.z + w0.w * a.w;
            acc1[b] += w1.x * a.x + w1.y * a.y + w1.z * a.z + w1.w * a.w;
        }
    }
#pragma unroll
    for (int b0 = 0; b0 < BZ; b0 += 2) {
#pragma unroll
        for (int off = 32; off > 0; off >>= 1) {
            acc0[b0 + 0] += __shfl_xor(acc0[b0 + 0], off, 64);
            acc0[b0 + 1] += __shfl_xor(acc0[b0 + 1], off, 64);
            acc1[b0 + 0] += __shfl_xor(acc1[b0 + 0], off, 64);
            acc1[b0 + 1] += __shfl_xor(acc1[b0 + 1], off, 64);
        }
    }
}

// ---- kernel A: REP_S reps of unchanged body --------------------------------
__global__ __launch_bounds__(256) void kA(const float* __restrict__ Wg,
                                          const float* __restrict__ Wo,
                                          const float* __restrict__ tgt,
                                          float* __restrict__ proj,
                                          float* __restrict__ tpart) {
    __shared__ float al[BZ][260];
    const int t = threadIdx.x, lane = t & 63, wave = t >> 6;
    const int r0 = blockIdx.x * 8 + wave * 2;
    const bool isWg = (r0 < DIM);
    const float* W0 = isWg ? &Wg[(size_t)r0 * DIM]
                           : &Wo[(size_t)(r0 - DIM) * (2 * DIM) + DIM];
    const float* W1 = isWg ? &Wg[(size_t)(r0 + 1) * DIM]
                           : &Wo[(size_t)(r0 + 1 - DIM) * (2 * DIM) + DIM];
    for (int rep = 0; rep < REP_S; ++rep) {
        asm volatile("" ::: "memory");   // forbid cross-rep CSE
        float acc0[BZ], acc1[BZ];
        rowmv(W0, W1, tgt, al, acc0, acc1, lane, wave);
        if (lane == 0) {
            if (isWg) {
#pragma unroll
                for (int b = 0; b < BZ; ++b) {
                    proj[b * DIM + r0]     = acc0[b];
                    proj[b * DIM + r0 + 1] = acc1[b];
                }
            } else {
#pragma unroll
                for (int b = 0; b < BZ; ++b) {
                    tpart[b * DIM + (r0 - DIM)]     = acc0[b];
                    tpart[b * DIM + (r0 - DIM) + 1] = acc1[b];
                }
            }
        }
    }
}

// ---- kernel B: REP_S reps ---------------------------------------------------
__global__ __launch_bounds__(256) void kB(const float* __restrict__ Wo,
                                          const float* __restrict__ c_ws,
                                          const float* __restrict__ tpart,
                                          float* __restrict__ outp) {
    __shared__ float al[BZ][260];
    const int t = threadIdx.x, lane = t & 63, wave = t >> 6;
    const int d0 = blockIdx.x * 8 + wave * 2;
    for (int rep = 0; rep < REP_S; ++rep) {
        asm volatile("" ::: "memory");
        float acc0[BZ], acc1[BZ];
        rowmv(&Wo[(size_t)d0 * (2 * DIM)], &Wo[(size_t)(d0 + 1) * (2 * DIM)],
              c_ws, al, acc0, acc1, lane, wave);
        if (lane == 0) {
#pragma unroll
            for (int b = 0; b < BZ; ++b) {
                outp[b * DIM + d0]     = acc0[b] + tpart[b * DIM + d0];
                outp[b * DIM + d0 + 1] = acc1[b] + tpart[b * DIM + d0 + 1];
            }
        }
    }
}

// ---- flash: R5 burst design, PLAIN cached loads (NT ablation), REP_F reps --
__global__ __launch_bounds__(256, 2) void k_flash(const float* __restrict__ src,
                                                  const float* __restrict__ proj,
                                                  const int* __restrict__ lens,
                                                  float* __restrict__ scores,
                                                  float* __restrict__ part_ml,
                                                  float* __restrict__ part_c) {
    __shared__ float s_c[4][1024];
    __shared__ float s_ml[4][2];
    const int blk = blockIdx.x;
    const int b = blk & 31;
    const int g = blk >> 5;
    const int t = threadIdx.x, lane = t & 63, wave = t >> 6;
    const int len = lens[b];
    const int r0 = (g * len) >> 6;
    const int r1 = ((g + 1) * len) >> 6;
    const int n  = r1 - r0;
    int nb = n - 8 * wave; nb = nb < 0 ? 0 : (nb > 8 ? 8 : nb);
    const float* sb = src + ((size_t)b * SRC_LEN + r0 + 8 * wave) * DIM;

    for (int rep = 0; rep < REP_F; ++rep) {
        asm volatile("" ::: "memory");   // force re-load each rep
        f4 pj[4];
#pragma unroll
        for (int q = 0; q < 4; ++q)
            pj[q] = *(const f4*)&proj[b * DIM + (q * 64 + lane) * 4];

        f4 v[8][4];
#pragma unroll
        for (int r = 0; r < 8; ++r) {
            if (r < nb) {
#pragma unroll
                for (int q = 0; q < 4; ++q)
                    v[r][q] = *(const f4*)&sb[r * DIM + (q * 64 + lane) * 4];
            }
        }
        float sc[8];
#pragma unroll
        for (int r = 0; r < 8; ++r) {
            if (r < nb) {
                const f4 d = v[r][0] * pj[0] + v[r][1] * pj[1] +
                             v[r][2] * pj[2] + v[r][3] * pj[3];
                sc[r] = d.x + d.y + d.z + d.w;
            } else {
                sc[r] = -INFINITY;
            }
        }
#pragma unroll
        for (int off = 32; off > 0; off >>= 1) {
#pragma unroll
            for (int r = 0; r < 8; ++r) sc[r] += __shfl_xor(sc[r], off, 64);
        }
        if (lane == 0) {
#pragma unroll
            for (int r = 0; r < 8; ++r)
                if (r < nb) scores[b * SRC_LEN + r0 + 8 * wave + r] = sc[r];
        }

        float m = -INFINITY, l = 0.f;
        f4 c[4] = {{0.f,0.f,0.f,0.f},{0.f,0.f,0.f,0.f},{0.f,0.f,0.f,0.f},{0.f,0.f,0.f,0.f}};
        if (nb > 0) {
#pragma unroll
            for (int r = 0; r < 8; ++r) m = fmaxf(m, sc[r]);
            float w[8];
#pragma unroll
            for (int r = 0; r < 8; ++r) { w[r] = __expf(sc[r] - m); l += w[r]; }
#pragma unroll
            for (int r = 0; r < 8; ++r) {
                if (r < nb) {
#pragma unroll
                    for (int q = 0; q < 4; ++q) c[q] += w[r] * v[r][q];
                }
            }
        }

        __syncthreads();   // protect s_c across reps
#pragma unroll
        for (int q = 0; q < 4; ++q)
            *(f4*)&s_c[wave][(q * 64 + lane) * 4] = c[q];
        if (lane == 0) { s_ml[wave][0] = m; s_ml[wave][1] = l; }
        __syncthreads();

        float M = fmaxf(fmaxf(s_ml[0][0], s_ml[1][0]), fmaxf(s_ml[2][0], s_ml[3][0]));
        float L = 0.f;
        f4 acc = {0.f, 0.f, 0.f, 0.f};
#pragma unroll
        for (int wv = 0; wv < 4; ++wv) {
            const float mw = s_ml[wv][0];
            const float e = (mw == -INFINITY) ? 0.f : __expf(mw - M);
            L += e * s_ml[wv][1];
            const f4 cv = *(const f4*)&s_c[wv][t * 4];
            acc += e * cv;
        }
        if (t == 0) { part_ml[2 * blk] = M; part_ml[2 * blk + 1] = L; }
        if (M > -INFINITY)
            *(f4*)&part_c[(size_t)blk * DIM + t * 4] = acc;
    }
}

// ---- merge: REP_S reps ------------------------------------------------------
__global__ __launch_bounds__(256) void k_merge(const float* __restrict__ part_ml,
                                               const float* __restrict__ part_c,
                                               const float* __restrict__ scores,
                                               const int* __restrict__ lens,
                                               float* __restrict__ c_ws,
                                               float* __restrict__ out_align) {
    __shared__ float s_m[NSPAN], s_l[NSPAN];
    const int b = blockIdx.x & 31;
    const int slice = blockIdx.x >> 5;
    const int t = threadIdx.x;
    for (int rep = 0; rep < REP_S; ++rep) {
        asm volatile("" ::: "memory");
        __syncthreads();   // protect s_m/s_l across reps
        if (t < NSPAN) {
            s_m[t] = part_ml[2 * (t * BZ + b)];
            s_l[t] = part_ml[2 * (t * BZ + b) + 1];
        }
        __syncthreads();
        float M = -INFINITY;
#pragma unroll
        for (int i = 0; i < NSPAN; ++i) M = fmaxf(M, s_m[i]);
        float L = 0.f;
#pragma unroll
        for (int i = 0; i < NSPAN; ++i)
            if (s_m[i] > -INFINITY) L += __expf(s_m[i] - M) * s_l[i];
        const float invL = 1.f / L;

        const int col = slice * 256 + t;
        float acc = 0.f;
        for (int i = 0; i < NSPAN; ++i) {
            if (s_m[i] > -INFINITY)
                acc += __expf(s_m[i] - M) * part_c[(size_t)(i * BZ + b) * DIM + col];
        }
        c_ws[b * DIM + col] = acc * invL;

        const int len = lens[b];
#pragma unroll
        for (int u = 0; u < 2; ++u) {
            const int s = slice * 512 + u * 256 + t;
            float a = 0.f;
            if (s < len) a = __expf(scores[b * SRC_LEN + s] - M) * invL;
            out_align[b * SRC_LEN + s] = a;
        }
    }
}

extern "C" void kernel_launch(void* const* d_in, const int* in_sizes, int n_in,
                              void* d_out, int out_size, void* d_ws, size_t ws_size,
                              hipStream_t stream) {
    const float* src = (const float*)d_in[0];
    const float* tgt = (const float*)d_in[1];
    const float* Wg  = (const float*)d_in[2];
    const float* Wo  = (const float*)d_in[3];
    const int*   len = (const int*)d_in[4];
    float* out = (float*)d_out;

    float* ws = (float*)d_ws;
    float* proj    = ws;                               // 32*1024
    float* scores  = proj + BZ * DIM;                  // 32*2048
    float* part_ml = scores + BZ * SRC_LEN;            // 2048*2
    float* part_c  = part_ml + BZ * NSPAN * 2;         // 2048*1024 (8 MB)
    float* c_ws    = part_c + (size_t)BZ * NSPAN * DIM;
    float* tpart   = c_ws + BZ * DIM;

    kA     <<<256,         256, 0, stream>>>(Wg, Wo, tgt, proj, tpart);
    k_flash<<<BZ * NSPAN,  256, 0, stream>>>(src, proj, len, scores, part_ml, part_c);
    k_merge<<<128,         256, 0, stream>>>(part_ml, part_c, scores, len, c_ws, out + BZ * DIM);
    kB     <<<128,         256, 0, stream>>>(Wo, c_ws, tpart, out);
}

// Round 10
// 113.211 us; speedup vs baseline: 5.7084x; 5.7084x over previous
//
#include <hip/hip_runtime.h>
#include <math.h>

#define BZ 32
#define SRC_LEN 2048
#define DIM 1024
#define NSPAN 64

typedef float f4 __attribute__((ext_vector_type(4)));

// ---- kernel A: wave-per-row, global-direct, no LDS/syncs -------------------
// rows 0..1023    -> proj[b][r]        = Wg[r] . tgt[b]
// rows 1024..2047 -> tpart[b][r-1024]  = Wo[r-1024][1024:] . tgt[b]
// grid 512 blocks x 256 thr (4 waves, wave owns 1 row).
__global__ __launch_bounds__(256) void kA(const float* __restrict__ Wg,
                                          const float* __restrict__ Wo,
                                          const float* __restrict__ tgt,
                                          float* __restrict__ proj,
                                          float* __restrict__ tpart) {
    const int t = threadIdx.x, lane = t & 63, wave = t >> 6;
    const int r = blockIdx.x * 4 + wave;          // 0..2047
    const bool isWg = (r < DIM);
    const float* Wrow = isWg ? &Wg[(size_t)r * DIM]
                             : &Wo[(size_t)(r - DIM) * (2 * DIM) + DIM];
    float acc[BZ];
#pragma unroll
    for (int b = 0; b < BZ; ++b) acc[b] = 0.f;

    for (int ks = 0; ks < 4; ++ks) {              // k chunk = ks*256 + lane*4
        const int ko = ks * 256 + lane * 4;
        const f4 wv = *(const f4*)&Wrow[ko];
#pragma unroll
        for (int b = 0; b < BZ; ++b) {            // 32 independent loads in flight
            const f4 a = *(const f4*)&tgt[b * DIM + ko];
            const f4 p = wv * a;
            acc[b] += p.x + p.y + p.z + p.w;
        }
    }
#pragma unroll
    for (int b = 0; b < BZ; ++b) {
#pragma unroll
        for (int off = 32; off > 0; off >>= 1)
            acc[b] += __shfl_xor(acc[b], off, 64);
    }
    if (lane == 0) {
        float* dst = isWg ? &proj[r] : &tpart[r - DIM];
#pragma unroll
        for (int b = 0; b < BZ; ++b) dst[b * DIM] = acc[b];
    }
}

// ---- kernel B: out = c@Wo_left^T + tpart, wave-per-row ---------------------
// FIX vs R9: K=1024 only (c part). tgt part comes from tpart (computed in kA).
// grid 256 blocks x 256 thr (wave owns 1 of 1024 Wo rows).
__global__ __launch_bounds__(256) void kB(const float* __restrict__ Wo,
                                          const float* __restrict__ c_ws,
                                          const float* __restrict__ tpart,
                                          float* __restrict__ outp) {
    const int t = threadIdx.x, lane = t & 63, wave = t >> 6;
    const int d = blockIdx.x * 4 + wave;          // 0..1023
    const float* Wrow = &Wo[(size_t)d * (2 * DIM)];   // left half: cols 0..1023
    float acc[BZ];
#pragma unroll
    for (int b = 0; b < BZ; ++b) acc[b] = 0.f;

    for (int ks = 0; ks < 4; ++ks) {              // c part only (K=1024)
        const int ko = ks * 256 + lane * 4;
        const f4 wv = *(const f4*)&Wrow[ko];
#pragma unroll
        for (int b = 0; b < BZ; ++b) {
            const f4 a = *(const f4*)&c_ws[b * DIM + ko];
            const f4 p = wv * a;
            acc[b] += p.x + p.y + p.z + p.w;
        }
    }
#pragma unroll
    for (int b = 0; b < BZ; ++b) {
#pragma unroll
        for (int off = 32; off > 0; off >>= 1)
            acc[b] += __shfl_xor(acc[b], off, 64);
    }
    if (lane == 0) {
#pragma unroll
        for (int b = 0; b < BZ; ++b)
            outp[b * DIM + d] = acc[b] + tpart[b * DIM + d];
    }
}

// ---- flash: R8 body (plain loads), part_c ALWAYS written -------------------
__global__ __launch_bounds__(256, 2) void k_flash(const float* __restrict__ src,
                                                  const float* __restrict__ proj,
                                                  const int* __restrict__ lens,
                                                  float* __restrict__ scores,
                                                  float* __restrict__ part_ml,
                                                  float* __restrict__ part_c) {
    __shared__ float s_c[4][1024];
    __shared__ float s_ml[4][2];
    const int blk = blockIdx.x;
    const int b = blk & 31;
    const int g = blk >> 5;
    const int t = threadIdx.x, lane = t & 63, wave = t >> 6;
    const int len = lens[b];
    const int r0 = (g * len) >> 6;
    const int r1 = ((g + 1) * len) >> 6;   // union over g = [0, len)
    const int n  = r1 - r0;
    int nb = n - 8 * wave; nb = nb < 0 ? 0 : (nb > 8 ? 8 : nb);
    const float* sb = src + ((size_t)b * SRC_LEN + r0 + 8 * wave) * DIM;

    f4 pj[4];
#pragma unroll
    for (int q = 0; q < 4; ++q)
        pj[q] = *(const f4*)&proj[b * DIM + (q * 64 + lane) * 4];

    f4 v[8][4];
#pragma unroll
    for (int r = 0; r < 8; ++r) {
        if (r < nb) {
#pragma unroll
            for (int q = 0; q < 4; ++q)
                v[r][q] = *(const f4*)&sb[r * DIM + (q * 64 + lane) * 4];
        }
    }
    float sc[8];
#pragma unroll
    for (int r = 0; r < 8; ++r) {
        if (r < nb) {
            const f4 d = v[r][0] * pj[0] + v[r][1] * pj[1] +
                         v[r][2] * pj[2] + v[r][3] * pj[3];
            sc[r] = d.x + d.y + d.z + d.w;
        } else {
            sc[r] = -INFINITY;
        }
    }
#pragma unroll
    for (int off = 32; off > 0; off >>= 1) {
#pragma unroll
        for (int r = 0; r < 8; ++r) sc[r] += __shfl_xor(sc[r], off, 64);
    }
    if (lane == 0) {
#pragma unroll
        for (int r = 0; r < 8; ++r)
            if (r < nb) scores[b * SRC_LEN + r0 + 8 * wave + r] = sc[r];
    }

    float m = -INFINITY, l = 0.f;
    f4 c[4] = {{0.f,0.f,0.f,0.f},{0.f,0.f,0.f,0.f},{0.f,0.f,0.f,0.f},{0.f,0.f,0.f,0.f}};
    if (nb > 0) {
#pragma unroll
        for (int r = 0; r < 8; ++r) m = fmaxf(m, sc[r]);
        float w[8];
#pragma unroll
        for (int r = 0; r < 8; ++r) { w[r] = __expf(sc[r] - m); l += w[r]; }
#pragma unroll
        for (int r = 0; r < 8; ++r) {
            if (r < nb) {
#pragma unroll
                for (int q = 0; q < 4; ++q) c[q] += w[r] * v[r][q];
            }
        }
    }

#pragma unroll
    for (int q = 0; q < 4; ++q)
        *(f4*)&s_c[wave][(q * 64 + lane) * 4] = c[q];
    if (lane == 0) { s_ml[wave][0] = m; s_ml[wave][1] = l; }
    __syncthreads();

    float M = fmaxf(fmaxf(s_ml[0][0], s_ml[1][0]), fmaxf(s_ml[2][0], s_ml[3][0]));
    float L = 0.f;
    f4 acc = {0.f, 0.f, 0.f, 0.f};
#pragma unroll
    for (int wv = 0; wv < 4; ++wv) {
        const float mw = s_ml[wv][0];
        const float e = (mw == -INFINITY) ? 0.f : __expf(mw - M);
        L += e * s_ml[wv][1];
        const f4 cv = *(const f4*)&s_c[wv][t * 4];
        acc += e * cv;
    }
    if (t == 0) { part_ml[2 * blk] = M; part_ml[2 * blk + 1] = L; }
    *(f4*)&part_c[(size_t)blk * DIM + t * 4] = acc;   // ALWAYS (dead -> zeros)
}

// ---- merge: unrolled x8 independent loads, unconditional part_c reads ------
__global__ __launch_bounds__(256) void k_merge(const float* __restrict__ part_ml,
                                               const float* __restrict__ part_c,
                                               const float* __restrict__ scores,
                                               const int* __restrict__ lens,
                                               float* __restrict__ c_ws,
                                               float* __restrict__ out_align) {
    __shared__ float s_m[NSPAN], s_l[NSPAN];
    const int b = blockIdx.x & 31;
    const int slice = blockIdx.x >> 5;
    const int t = threadIdx.x;
    if (t < NSPAN) {
        s_m[t] = part_ml[2 * (t * BZ + b)];
        s_l[t] = part_ml[2 * (t * BZ + b) + 1];
    }
    __syncthreads();
    float M = -INFINITY;
#pragma unroll
    for (int i = 0; i < NSPAN; ++i) M = fmaxf(M, s_m[i]);
    float L = 0.f;
#pragma unroll
    for (int i = 0; i < NSPAN; ++i)
        if (s_m[i] > -INFINITY) L += __expf(s_m[i] - M) * s_l[i];
    const float invL = 1.f / L;

    const int col = slice * 256 + t;
    float acc = 0.f;
    for (int i0 = 0; i0 < NSPAN; i0 += 8) {
        float e[8], vv[8];
#pragma unroll
        for (int u = 0; u < 8; ++u)
            e[u] = (s_m[i0 + u] > -INFINITY) ? __expf(s_m[i0 + u] - M) : 0.f;
#pragma unroll
        for (int u = 0; u < 8; ++u)      // 8 independent in-flight loads
            vv[u] = part_c[(size_t)((i0 + u) * BZ + b) * DIM + col];
#pragma unroll
        for (int u = 0; u < 8; ++u) acc += e[u] * vv[u];
    }
    c_ws[b * DIM + col] = acc * invL;

    const int len = lens[b];
#pragma unroll
    for (int u = 0; u < 2; ++u) {
        const int s = slice * 512 + u * 256 + t;
        float a = 0.f;
        if (s < len) a = __expf(scores[b * SRC_LEN + s] - M) * invL;
        out_align[b * SRC_LEN + s] = a;
    }
}

extern "C" void kernel_launch(void* const* d_in, const int* in_sizes, int n_in,
                              void* d_out, int out_size, void* d_ws, size_t ws_size,
                              hipStream_t stream) {
    const float* src = (const float*)d_in[0];   // (32, 2048, 1024)
    const float* tgt = (const float*)d_in[1];   // (32, 1, 1024)
    const float* Wg  = (const float*)d_in[2];   // (1024, 1024)
    const float* Wo  = (const float*)d_in[3];   // (1024, 2048)
    const int*   len = (const int*)d_in[4];     // (32,)
    float* out = (float*)d_out;                 // attn_h [0,32768) ++ align

    float* ws = (float*)d_ws;
    float* proj    = ws;                               // 32*1024
    float* scores  = proj + BZ * DIM;                  // 32*2048
    float* part_ml = scores + BZ * SRC_LEN;            // 2048*2
    float* part_c  = part_ml + BZ * NSPAN * 2;         // 2048*1024 (8 MB)
    float* c_ws    = part_c + (size_t)BZ * NSPAN * DIM;
    float* tpart   = c_ws + BZ * DIM;

    kA     <<<512,         256, 0, stream>>>(Wg, Wo, tgt, proj, tpart);
    k_flash<<<BZ * NSPAN,  256, 0, stream>>>(src, proj, len, scores, part_ml, part_c);
    k_merge<<<128,         256, 0, stream>>>(part_ml, part_c, scores, len, c_ws, out + BZ * DIM);
    kB     <<<256,         256, 0, stream>>>(Wo, c_ws, tpart, out);
}

// Round 11
// 59.820 us; speedup vs baseline: 10.8034x; 1.8925x over previous
//
#include <hip/hip_runtime.h>
#include <math.h>

#define BZ 32
#define SRC_LEN 2048
#define DIM 1024
#define NSPAN 64

typedef float f4 __attribute__((ext_vector_type(4)));

// ---- kernel A: 1-wave blocks, 2 W-rows/block, activations direct -----------
// virtual rows 0..1023   -> proj[b][r]       = Wg[r] . tgt[b]
// virtual rows 1024..2047-> tpart[b][r-1024] = Wo[r-1024][1024:] . tgt[b]
// grid 1024 blocks x 64 thr (4 blocks/CU).
__global__ __launch_bounds__(64) void kA(const float* __restrict__ Wg,
                                         const float* __restrict__ Wo,
                                         const float* __restrict__ tgt,
                                         float* __restrict__ proj,
                                         float* __restrict__ tpart) {
    const int lane = threadIdx.x;
    const int r0 = blockIdx.x * 2;
    const int r1 = r0 + 1;
    const float* W0 = (r0 < DIM) ? &Wg[(size_t)r0 * DIM]
                                 : &Wo[(size_t)(r0 - DIM) * (2 * DIM) + DIM];
    const float* W1 = (r1 < DIM) ? &Wg[(size_t)r1 * DIM]
                                 : &Wo[(size_t)(r1 - DIM) * (2 * DIM) + DIM];
    f4 w0[4], w1[4];
#pragma unroll
    for (int i = 0; i < 4; ++i) {
        w0[i] = *(const f4*)&W0[i * 256 + lane * 4];
        w1[i] = *(const f4*)&W1[i * 256 + lane * 4];
    }
    float acc0[BZ], acc1[BZ];
#pragma unroll
    for (int b = 0; b < BZ; ++b) { acc0[b] = 0.f; acc1[b] = 0.f; }
#pragma unroll
    for (int b = 0; b < BZ; ++b) {
#pragma unroll
        for (int i = 0; i < 4; ++i) {
            const f4 a = *(const f4*)&tgt[b * DIM + i * 256 + lane * 4];
            acc0[b] = fmaf(w0[i].x, a.x, acc0[b]);
            acc0[b] = fmaf(w0[i].y, a.y, acc0[b]);
            acc0[b] = fmaf(w0[i].z, a.z, acc0[b]);
            acc0[b] = fmaf(w0[i].w, a.w, acc0[b]);
            acc1[b] = fmaf(w1[i].x, a.x, acc1[b]);
            acc1[b] = fmaf(w1[i].y, a.y, acc1[b]);
            acc1[b] = fmaf(w1[i].z, a.z, acc1[b]);
            acc1[b] = fmaf(w1[i].w, a.w, acc1[b]);
        }
    }
#pragma unroll
    for (int b = 0; b < BZ; ++b) {
#pragma unroll
        for (int off = 32; off > 0; off >>= 1) {
            acc0[b] += __shfl_xor(acc0[b], off, 64);
            acc1[b] += __shfl_xor(acc1[b], off, 64);
        }
    }
    if (lane == 0) {
        if (r0 < DIM) {
#pragma unroll
            for (int b = 0; b < BZ; ++b) {
                proj[b * DIM + r0] = acc0[b];
                proj[b * DIM + r1] = acc1[b];
            }
        } else {
#pragma unroll
            for (int b = 0; b < BZ; ++b) {
                tpart[b * DIM + (r0 - DIM)] = acc0[b];
                tpart[b * DIM + (r1 - DIM)] = acc1[b];
            }
        }
    }
}

// ---- kernel B: out = c@Wo_left^T + tpart; 1-wave blocks, 2 rows/block ------
// grid 512 blocks x 64 thr (2 blocks/CU).
__global__ __launch_bounds__(64) void kB(const float* __restrict__ Wo,
                                         const float* __restrict__ c_ws,
                                         const float* __restrict__ tpart,
                                         float* __restrict__ outp) {
    const int lane = threadIdx.x;
    const int d0 = blockIdx.x * 2;
    const int d1 = d0 + 1;
    const float* W0 = &Wo[(size_t)d0 * (2 * DIM)];   // left half (cols 0..1023)
    const float* W1 = &Wo[(size_t)d1 * (2 * DIM)];
    f4 w0[4], w1[4];
#pragma unroll
    for (int i = 0; i < 4; ++i) {
        w0[i] = *(const f4*)&W0[i * 256 + lane * 4];
        w1[i] = *(const f4*)&W1[i * 256 + lane * 4];
    }
    float acc0[BZ], acc1[BZ];
#pragma unroll
    for (int b = 0; b < BZ; ++b) { acc0[b] = 0.f; acc1[b] = 0.f; }
#pragma unroll
    for (int b = 0; b < BZ; ++b) {
#pragma unroll
        for (int i = 0; i < 4; ++i) {
            const f4 a = *(const f4*)&c_ws[b * DIM + i * 256 + lane * 4];
            acc0[b] = fmaf(w0[i].x, a.x, acc0[b]);
            acc0[b] = fmaf(w0[i].y, a.y, acc0[b]);
            acc0[b] = fmaf(w0[i].z, a.z, acc0[b]);
            acc0[b] = fmaf(w0[i].w, a.w, acc0[b]);
            acc1[b] = fmaf(w1[i].x, a.x, acc1[b]);
            acc1[b] = fmaf(w1[i].y, a.y, acc1[b]);
            acc1[b] = fmaf(w1[i].z, a.z, acc1[b]);
            acc1[b] = fmaf(w1[i].w, a.w, acc1[b]);
        }
    }
#pragma unroll
    for (int b = 0; b < BZ; ++b) {
#pragma unroll
        for (int off = 32; off > 0; off >>= 1) {
            acc0[b] += __shfl_xor(acc0[b], off, 64);
            acc1[b] += __shfl_xor(acc1[b], off, 64);
        }
    }
    if (lane == 0) {
#pragma unroll
        for (int b = 0; b < BZ; ++b) {
            outp[b * DIM + d0] = acc0[b] + tpart[b * DIM + d0];
            outp[b * DIM + d1] = acc1[b] + tpart[b * DIM + d1];
        }
    }
}

// ---- flash: R10 version verbatim (21.2 us, streaming floor) ----------------
__global__ __launch_bounds__(256, 2) void k_flash(const float* __restrict__ src,
                                                  const float* __restrict__ proj,
                                                  const int* __restrict__ lens,
                                                  float* __restrict__ scores,
                                                  float* __restrict__ part_ml,
                                                  float* __restrict__ part_c) {
    __shared__ float s_c[4][1024];
    __shared__ float s_ml[4][2];
    const int blk = blockIdx.x;
    const int b = blk & 31;
    const int g = blk >> 5;
    const int t = threadIdx.x, lane = t & 63, wave = t >> 6;
    const int len = lens[b];
    const int r0 = (g * len) >> 6;
    const int r1 = ((g + 1) * len) >> 6;   // union over g = [0, len)
    const int n  = r1 - r0;
    int nb = n - 8 * wave; nb = nb < 0 ? 0 : (nb > 8 ? 8 : nb);
    const float* sb = src + ((size_t)b * SRC_LEN + r0 + 8 * wave) * DIM;

    f4 pj[4];
#pragma unroll
    for (int q = 0; q < 4; ++q)
        pj[q] = *(const f4*)&proj[b * DIM + (q * 64 + lane) * 4];

    f4 v[8][4];
#pragma unroll
    for (int r = 0; r < 8; ++r) {
        if (r < nb) {
#pragma unroll
            for (int q = 0; q < 4; ++q)
                v[r][q] = *(const f4*)&sb[r * DIM + (q * 64 + lane) * 4];
        }
    }
    float sc[8];
#pragma unroll
    for (int r = 0; r < 8; ++r) {
        if (r < nb) {
            const f4 d = v[r][0] * pj[0] + v[r][1] * pj[1] +
                         v[r][2] * pj[2] + v[r][3] * pj[3];
            sc[r] = d.x + d.y + d.z + d.w;
        } else {
            sc[r] = -INFINITY;
        }
    }
#pragma unroll
    for (int off = 32; off > 0; off >>= 1) {
#pragma unroll
        for (int r = 0; r < 8; ++r) sc[r] += __shfl_xor(sc[r], off, 64);
    }
    if (lane == 0) {
#pragma unroll
        for (int r = 0; r < 8; ++r)
            if (r < nb) scores[b * SRC_LEN + r0 + 8 * wave + r] = sc[r];
    }

    float m = -INFINITY, l = 0.f;
    f4 c[4] = {{0.f,0.f,0.f,0.f},{0.f,0.f,0.f,0.f},{0.f,0.f,0.f,0.f},{0.f,0.f,0.f,0.f}};
    if (nb > 0) {
#pragma unroll
        for (int r = 0; r < 8; ++r) m = fmaxf(m, sc[r]);
        float w[8];
#pragma unroll
        for (int r = 0; r < 8; ++r) { w[r] = __expf(sc[r] - m); l += w[r]; }
#pragma unroll
        for (int r = 0; r < 8; ++r) {
            if (r < nb) {
#pragma unroll
                for (int q = 0; q < 4; ++q) c[q] += w[r] * v[r][q];
            }
        }
    }

#pragma unroll
    for (int q = 0; q < 4; ++q)
        *(f4*)&s_c[wave][(q * 64 + lane) * 4] = c[q];
    if (lane == 0) { s_ml[wave][0] = m; s_ml[wave][1] = l; }
    __syncthreads();

    float M = fmaxf(fmaxf(s_ml[0][0], s_ml[1][0]), fmaxf(s_ml[2][0], s_ml[3][0]));
    float L = 0.f;
    f4 acc = {0.f, 0.f, 0.f, 0.f};
#pragma unroll
    for (int wv = 0; wv < 4; ++wv) {
        const float mw = s_ml[wv][0];
        const float e = (mw == -INFINITY) ? 0.f : __expf(mw - M);
        L += e * s_ml[wv][1];
        const f4 cv = *(const f4*)&s_c[wv][t * 4];
        acc += e * cv;
    }
    if (t == 0) { part_ml[2 * blk] = M; part_ml[2 * blk + 1] = L; }
    *(f4*)&part_c[(size_t)blk * DIM + t * 4] = acc;   // ALWAYS (dead -> zeros)
}

// ---- merge: 512 one-wave blocks (b, 16 col-slices), in-register M/L --------
__global__ __launch_bounds__(64) void k_merge(const float* __restrict__ part_ml,
                                              const float* __restrict__ part_c,
                                              const float* __restrict__ scores,
                                              const int* __restrict__ lens,
                                              float* __restrict__ c_ws,
                                              float* __restrict__ out_align) {
    __shared__ float se[NSPAN];
    const int b = blockIdx.x & 31;
    const int slice = blockIdx.x >> 5;         // 0..15
    const int lane = threadIdx.x;              // 0..63 == span id

    const float m_t = part_ml[2 * (lane * BZ + b)];
    const float l_t = part_ml[2 * (lane * BZ + b) + 1];
    float M = m_t;
#pragma unroll
    for (int off = 32; off > 0; off >>= 1) M = fmaxf(M, __shfl_xor(M, off, 64));
    const float e_t = (m_t > -INFINITY) ? __expf(m_t - M) : 0.f;
    float L = e_t * l_t;
#pragma unroll
    for (int off = 32; off > 0; off >>= 1) L += __shfl_xor(L, off, 64);
    const float invL = 1.f / L;

    se[lane] = e_t;
    __syncthreads();

    const int col = slice * 64 + lane;
    float acc = 0.f;
    for (int i0 = 0; i0 < NSPAN; i0 += 8) {
        float vv[8];
#pragma unroll
        for (int u = 0; u < 8; ++u)          // 8 independent loads in flight
            vv[u] = part_c[(size_t)((i0 + u) * BZ + b) * DIM + col];
#pragma unroll
        for (int u = 0; u < 8; ++u) acc += se[i0 + u] * vv[u];
    }
    c_ws[b * DIM + col] = acc * invL;

    const int len = lens[b];
#pragma unroll
    for (int u = 0; u < 2; ++u) {
        const int s = slice * 128 + u * 64 + lane;
        float a = 0.f;
        if (s < len) a = __expf(scores[b * SRC_LEN + s] - M) * invL;
        out_align[b * SRC_LEN + s] = a;
    }
}

extern "C" void kernel_launch(void* const* d_in, const int* in_sizes, int n_in,
                              void* d_out, int out_size, void* d_ws, size_t ws_size,
                              hipStream_t stream) {
    const float* src = (const float*)d_in[0];   // (32, 2048, 1024)
    const float* tgt = (const float*)d_in[1];   // (32, 1, 1024)
    const float* Wg  = (const float*)d_in[2];   // (1024, 1024)
    const float* Wo  = (const float*)d_in[3];   // (1024, 2048)
    const int*   len = (const int*)d_in[4];     // (32,)
    float* out = (float*)d_out;                 // attn_h [0,32768) ++ align

    float* ws = (float*)d_ws;
    float* proj    = ws;                               // 32*1024
    float* scores  = proj + BZ * DIM;                  // 32*2048
    float* part_ml = scores + BZ * SRC_LEN;            // 2048*2
    float* part_c  = part_ml + BZ * NSPAN * 2;         // 2048*1024 (8 MB)
    float* c_ws    = part_c + (size_t)BZ * NSPAN * DIM;
    float* tpart   = c_ws + BZ * DIM;

    kA     <<<1024,        64,  0, stream>>>(Wg, Wo, tgt, proj, tpart);
    k_flash<<<BZ * NSPAN,  256, 0, stream>>>(src, proj, len, scores, part_ml, part_c);
    k_merge<<<512,         64,  0, stream>>>(part_ml, part_c, scores, len, c_ws, out + BZ * DIM);
    kB     <<<512,         64,  0, stream>>>(Wo, c_ws, tpart, out);
}